// Round 2
// baseline (1422.630 us; speedup 1.0000x reference)
//
#include <hip/hip_runtime.h>

#define D_INPUT 768
#define D_HID   16384
#define BATCH   8192
#define TOPK    32
#define ROWS_PB 4

using f32x4     = __attribute__((ext_vector_type(4))) float;
using bf16x8    = __attribute__((ext_vector_type(8))) __bf16;
using ushort8_t = __attribute__((ext_vector_type(8))) unsigned short;

__device__ __forceinline__ unsigned short f2bf(float f) {
  union { float f; unsigned u; } v{f};
  return (unsigned short)((v.u + 0x7FFFu + ((v.u >> 16) & 1u)) >> 16);  // RNE
}
__device__ __forceinline__ float bf2f(unsigned short u) {
  union { unsigned u; float f; } v{(unsigned)u << 16};
  return v.f;
}

// async global->LDS, 16B per lane; LDS dest = wave-uniform base + lane*16.
__device__ __forceinline__ void async_copy16(const void* g, void* l) {
  __builtin_amdgcn_global_load_lds(
      (__attribute__((address_space(1))) void*)(unsigned long long)g,
      (__attribute__((address_space(3))) void*)(unsigned)(unsigned long long)l,
      16, 0, 0);
}

// Barrier that waits LDS ops only (lgkmcnt) and leaves global loads (vmcnt)
// in flight -- __syncthreads() drains vmcnt(0) and would kill the Z-row
// register prefetch. All intra-block communication is via LDS, so this is
// sufficient. Pattern per m139/m201 (raw s_barrier + manual waitcnt).
#define BAR() do {                                            \
    asm volatile("s_waitcnt lgkmcnt(0)" ::: "memory");        \
    __builtin_amdgcn_s_barrier();                             \
    asm volatile("" ::: "memory");                            \
  } while (0)

// Replica of OpenBLAS sgemm on Zen4/Zen5 hosts (SkylakeX/Cooperlake kernels):
// SGEMM_DEFAULT_Q = 320 -> K panels [320, 224, 224]; each panel a single
// ascending fma chain; C updated panel-by-panel -> ((p0 + p1) + p2).
// The three chains are INDEPENDENT -> interleaved for 3-way ILP (each chain's
// internal order untouched -> bit-identical result).
__device__ float blas_dot(const float* __restrict__ xr,
                          const float* __restrict__ wp) {
  float p0 = 0.f, p1 = 0.f, p2 = 0.f;
  #pragma unroll 4
  for (int i = 0; i < 224; ++i) {
    p0 = __builtin_fmaf(xr[i],       wp[i],       p0);
    p1 = __builtin_fmaf(xr[320 + i], wp[320 + i], p1);
    p2 = __builtin_fmaf(xr[544 + i], wp[544 + i], p2);
  }
  #pragma unroll 4
  for (int i = 224; i < 320; ++i) p0 = __builtin_fmaf(xr[i], wp[i], p0);
  return (p0 + p1) + p2;
}

// ---------------- fp32 -> bf16 convert (vectorized) ----------------
__global__ void cvt_f32_bf16(const float* __restrict__ in,
                             unsigned short* __restrict__ out, int n) {
  int i = (blockIdx.x * 256 + threadIdx.x) * 4;
  if (i < n) {
    float4 f = *(const float4*)(in + i);
    ushort4 o;
    o.x = f2bf(f.x); o.y = f2bf(f.y); o.z = f2bf(f.z); o.w = f2bf(f.w);
    *(ushort4*)(out + i) = o;
  }
}

// ---------------- W_dec [768][16384] -> WT bf16 [16384][768] ----------------
__global__ void transpose_wdec(const float* __restrict__ W,
                               unsigned short* __restrict__ WT) {
  __shared__ float tile[32][33];
  const int h0 = blockIdx.x * 32;   // hidden
  const int i0 = blockIdx.y * 32;   // d_in
  const int tx = threadIdx.x, ty = threadIdx.y;  // 32 x 8
  #pragma unroll
  for (int j = 0; j < 32; j += 8)
    tile[ty + j][tx] = W[(size_t)(i0 + ty + j) * D_HID + h0 + tx];
  __syncthreads();
  #pragma unroll
  for (int j = 0; j < 32; j += 8)
    WT[(size_t)(h0 + ty + j) * D_INPUT + i0 + tx] = f2bf(tile[tx][ty + j]);
}

// ---------------- encode: Z = relu(Xc * Wb^T + b_enc), bf16 MFMA ----------------
__global__ __launch_bounds__(256) void encode_kernel(
    const unsigned short* __restrict__ Xc,   // [rows][768] bf16 (chunk base)
    const unsigned short* __restrict__ Wb,   // [16384][768] bf16
    const float* __restrict__ b_enc,
    unsigned short* __restrict__ Z)          // [rows][16384] bf16, relu'd
{
  __shared__ unsigned short As[128 * 32];  // 8 KB, row-major [row][k]
  __shared__ unsigned short Bs[128 * 32];

  const int tid  = threadIdx.x;
  const int wave = tid >> 6;
  const int lane = tid & 63;
  const int tileN = blockIdx.x;
  const int tileM = blockIdx.y;

  const int e0 = wave * 512 + lane * 8;
  const int r0 = e0 >> 5;          // tile row 0..63 (second copy adds 64)
  const int k0 = e0 & 31;

  const unsigned short* gA = Xc + (size_t)(tileM * 128 + r0) * D_INPUT + k0;
  const unsigned short* gB = Wb + (size_t)(tileN * 128 + r0) * D_INPUT + k0;
  unsigned short* lA0 = As + wave * 512;         // wave-uniform LDS bases
  unsigned short* lA1 = As + wave * 512 + 2048;
  unsigned short* lB0 = Bs + wave * 512;
  unsigned short* lB1 = Bs + wave * 512 + 2048;

  const int wr = wave >> 1, wc = wave & 1;
  const int lrow = lane & 15;
  const int lk   = (lane >> 4) * 8;

  f32x4 acc[4][4] = {};

  for (int kt = 0; kt < D_INPUT / 32; ++kt) {
    __syncthreads();
    async_copy16(gA, lA0);
    async_copy16(gA + 64 * D_INPUT, lA1);
    async_copy16(gB, lB0);
    async_copy16(gB + 64 * D_INPUT, lB1);
    gA += 32; gB += 32;
    __builtin_amdgcn_s_waitcnt(0);
    __syncthreads();

    bf16x8 af[4], bfr[4];
    #pragma unroll
    for (int mf = 0; mf < 4; ++mf)
      af[mf] = __builtin_bit_cast(bf16x8,
        *(const ushort8_t*)(As + (wr * 64 + mf * 16 + lrow) * 32 + lk));
    #pragma unroll
    for (int nf = 0; nf < 4; ++nf)
      bfr[nf] = __builtin_bit_cast(bf16x8,
        *(const ushort8_t*)(Bs + (wc * 64 + nf * 16 + lrow) * 32 + lk));
    #pragma unroll
    for (int mf = 0; mf < 4; ++mf)
      #pragma unroll
      for (int nf = 0; nf < 4; ++nf)
        acc[mf][nf] = __builtin_amdgcn_mfma_f32_16x16x32_bf16(
            af[mf], bfr[nf], acc[mf][nf], 0, 0, 0);
  }

  // epilogue: C/D layout col=lane&15, row=(lane>>4)*4+reg (m89/m91-verified)
  const int rowBase = tileM * 128 + wr * 64;
  const int colBase = tileN * 128 + wc * 64;
  #pragma unroll
  for (int nf = 0; nf < 4; ++nf) {
    const int col = colBase + nf * 16 + lrow;
    const float bias = b_enc[col];
    #pragma unroll
    for (int mf = 0; mf < 4; ++mf) {
      const int row = rowBase + mf * 16 + (lane >> 4) * 4;
      #pragma unroll
      for (int i = 0; i < 4; ++i) {
        float v = acc[mf][nf][i] + bias;
        v = v > 0.f ? v : 0.f;
        Z[(size_t)(row + i) * D_HID + col] = f2bf(v);
      }
    }
  }
}

// Wave-0 suffix scan over a 256-bin histogram: find the highest bin b such
// that base + count(bins > b) + count(bin b) >= TOPK. Writes {bin, count
// strictly above bin} from the single winning lane.
__device__ __forceinline__ void scan_suffix(const unsigned int* __restrict__ h,
                                            int base, int* outBin, int* outCum,
                                            int l) {
  unsigned int h0 = h[255 - 4 * l];
  unsigned int h1 = h[254 - 4 * l];
  unsigned int h2 = h[253 - 4 * l];
  unsigned int h3 = h[252 - 4 * l];
  unsigned int c0 = h0, c1 = c0 + h1, c2 = c1 + h2, c3 = c2 + h3;
  unsigned int inc = c3;                       // inclusive scan of lane totals
  #pragma unroll
  for (int d = 1; d < 64; d <<= 1) {
    unsigned int o = __shfl_up(inc, d, 64);
    if (l >= d) inc += o;
  }
  unsigned int excl = (unsigned int)base + inc - c3;  // count above lane's bins
  int bFound = -1; int cumB = 0;
  if      (excl + c0 >= TOPK) { bFound = 255 - 4 * l; cumB = (int)excl; }
  else if (excl + c1 >= TOPK) { bFound = 254 - 4 * l; cumB = (int)(excl + c0); }
  else if (excl + c2 >= TOPK) { bFound = 253 - 4 * l; cumB = (int)(excl + c1); }
  else if (excl + c3 >= TOPK) { bFound = 252 - 4 * l; cumB = (int)(excl + c2); }
  unsigned long long m = __ballot(bFound >= 0);
  if (m) {
    int w = (int)__builtin_ctzll(m);           // lowest lane = highest bins
    if (l == w) { *outBin = bFound; *outCum = cumB; }
  } else if (l == 0) { *outBin = -1; *outCum = base; }
}

// ---------------- top-32: 4 rows/block, Z double-buffered in registers -------
// v3: the R1 kernel was lockstep-stall-bound (VALUBusy 27%, all resident
// blocks hit the same HBM-burst / atomic / blas phases simultaneously).
// Fix: per-block pipelining. Row r+1's Z loads are issued at the top of row
// r's processing and stay in flight across barriers (BAR() waits lgkm only).
// blas_dot recompute + output batched across 4 rows. Selection semantics
// identical to v2 (exact bf16 rank-32 + MARGIN band + OpenBLAS-replica fp32).
__global__ __launch_bounds__(256, 4) void topk_kernel(
    const unsigned short* __restrict__ Z,    // chunk base [rows][16384]
    const float* __restrict__ X,             // full fp32 [8192][768]
    const float* __restrict__ W_enc,         // fp32 [16384][768]
    const float* __restrict__ b_enc,
    int* __restrict__ sel_idx,               // [8192][32]
    float* __restrict__ sel_val,
    int rowOff)
{
  __shared__ __attribute__((aligned(16))) float xrow[ROWS_PB][D_INPUT]; // 12 KB
  __shared__ __attribute__((aligned(16))) unsigned int hist[256 * 8];   // 8 KB
  __shared__ unsigned int htot[256];          // 1 KB (pass-1 totals / pass-2 hist)
  __shared__ int   cand_idx[512];             // defs: rr*64+i, ambs: 256+rr*64+i
  __shared__ float cand_val[512];
  __shared__ int ndc[ROWS_PB], nac[ROWS_PB], occ[ROWS_PB];
  __shared__ int sB, sCum, sLo;
  __shared__ unsigned short sTr[ROWS_PB];

  const int tid   = threadIdx.x;
  const int lane  = tid & 63;
  const int rbase = blockIdx.x * ROWS_PB;     // row within chunk

  const ushort8_t* zsrc = (const ushort8_t*)(Z + (size_t)rbase * D_HID);
  ushort8_t zA[8], zB[8];
  #pragma unroll
  for (int j = 0; j < 8; ++j) zA[j] = zsrc[tid + j * 256];   // row 0

  // 4 consecutive X rows are contiguous: one coalesced float4 copy
  {
    const float4* xs = (const float4*)(X + (size_t)(rowOff + rbase) * D_INPUT);
    #pragma unroll
    for (int p = 0; p < 3; ++p)
      ((float4*)&xrow[0][0])[tid + p * 256] = xs[tid + p * 256];
  }
  #pragma unroll
  for (int c = 0; c < 8; ++c) hist[tid + c * 256] = 0;
  htot[tid] = 0;
  if (tid < ROWS_PB) { ndc[tid] = 0; nac[tid] = 0; occ[tid] = 0; }
  BAR();

  // ---- per-row processing (macro-free inlined helper) ----
  auto process_row = [&](ushort8_t* zc, ushort8_t* zn,
                         const ushort8_t* zsrcNext, int rr, bool pref) {
    if (pref) {                                // T14: issue next row's loads NOW
      #pragma unroll
      for (int j = 0; j < 8; ++j) zn[j] = zsrcNext[tid + j * 256];
    }
    // pass 1: high byte, 8-copy privatized (zeros excluded)
    #pragma unroll
    for (int j = 0; j < 8; ++j)
      #pragma unroll
      for (int e = 0; e < 8; ++e) {
        unsigned k = (unsigned short)zc[j][e];
        if (k) atomicAdd(&hist[((k >> 8) << 3) + (tid & 7)], 1u);
      }
    BAR();
    {
      const uint4* hp = (const uint4*)(hist + tid * 8);
      uint4 a = hp[0], b = hp[1];
      htot[tid] = a.x + a.y + a.z + a.w + b.x + b.y + b.z + b.w;
    }
    BAR();
    if (tid < 64) {
      scan_suffix(htot, 0, &sB, &sCum, lane);
    } else {                                   // clear hist for next row
      for (int c = tid - 64; c < 512; c += 192)
        ((uint4*)hist)[c] = make_uint4(0u, 0u, 0u, 0u);
    }
    BAR();
    const int bHi  = sB;
    const int cum1 = sCum;
    htot[tid] = 0;
    BAR();
    // pass 2: low byte within bin bHi (sparse -> single copy)
    if (bHi >= 0) {
      #pragma unroll
      for (int j = 0; j < 8; ++j)
        #pragma unroll
        for (int e = 0; e < 8; ++e) {
          unsigned k = (unsigned short)zc[j][e];
          if (k != 0 && (k >> 8) == (unsigned)bHi) atomicAdd(&htot[k & 255], 1u);
        }
    }
    BAR();
    if (bHi >= 0) {
      if (tid < 64) { int dummy; scan_suffix(htot, cum1, &sLo, &dummy, lane); }
    } else if (tid == 0) sLo = 0;
    BAR();
    const int T = (bHi >= 0) ? ((bHi << 8) | sLo) : 0;
    if (tid == 0) sTr[rr] = (unsigned short)T;
    const bool deg = (T == 0);                 // <32 positive activations
    const float v32 = bf2f((unsigned short)T);
    const float MARGIN = 0.025f;               // > 2*(bf16 quant + MFMA noise)
    const float vhi = v32 + MARGIN, vlo = v32 - MARGIN;
    // prune: k < (bHi-1)<<8  =>  v < bot(bHi)/4 < vlo  (valid for bHi>=0x3E,
    // since bot(0x3E)=0.125 and 0.125/4 < 0.125-0.025)
    const unsigned kmin = (bHi >= 0x3E) ? (((unsigned)bHi - 1u) << 8) : 1u;
    #pragma unroll
    for (int j = 0; j < 8; ++j)
      #pragma unroll
      for (int e = 0; e < 8; ++e) {
        unsigned k = (unsigned short)zc[j][e];
        if (k < kmin) continue;                // kmin>=1 also skips zeros
        const float v = bf2f((unsigned short)k);
        const int i = tid * 8 + j * 2048 + e;
        if (deg || v > vhi) {                  // provably in ref's top-32
          int p = atomicAdd(&ndc[rr], 1);
          if (p < 40) cand_idx[rr * 64 + p] = i;
        } else if (v >= vlo) {                 // boundary-ambiguous
          int p = atomicAdd(&nac[rr], 1);
          if (p < 64) cand_idx[256 + rr * 64 + p] = i;
        }
      }
    // no barrier: next row touches hist (cleared, double-barriered) only
  };

  process_row(zA, zB, zsrc + 1 * 2048, 0, true);
  process_row(zB, zA, zsrc + 2 * 2048, 1, true);
  process_row(zA, zB, zsrc + 3 * 2048, 2, true);
  process_row(zB, zA, nullptr,         3, false);
  BAR();

  // ---- batched OpenBLAS-replica fp32 recompute: all rows' candidates ----
  #pragma unroll
  for (int c = tid; c < 512; c += 256) {
    const int rr = (c >> 6) & 3;
    const int ii = c & 63;
    const bool isAmb = c >= 256;
    const int cnt = isAmb ? (nac[rr] < 64 ? nac[rr] : 64)
                          : (ndc[rr] < 40 ? ndc[rr] : 40);
    if (ii < cnt) {
      const int h = cand_idx[c];
      float acc = blas_dot(&xrow[rr][0], W_enc + (size_t)h * D_INPUT) + b_enc[h];
      cand_val[c] = acc > 0.f ? acc : 0.f;
    }
  }
  BAR();

  // ---- output: wave rr emits row rr ----
  {
    const int rr  = tid >> 6;
    const int row = rowOff + rbase + rr;
    const int nd  = ndc[rr] < 40 ? ndc[rr] : 40;
    const bool deg = (sTr[rr] == 0);
    const int na  = deg ? 0 : (nac[rr] < 64 ? nac[rr] : 64);
    const int need = TOPK - nd;
    if (lane < nd) {
      sel_idx[row * TOPK + lane] = cand_idx[rr * 64 + lane];
      sel_val[row * TOPK + lane] = cand_val[rr * 64 + lane];
    }
    if (lane < na) {
      const float v = cand_val[256 + rr * 64 + lane];
      const int   h = cand_idx[256 + rr * 64 + lane];
      int rank = 0;
      for (int j = 0; j < na; ++j) {
        const float vj = cand_val[256 + rr * 64 + j];
        const int   hj = cand_idx[256 + rr * 64 + j];
        if (vj > v || (vj == v && hj < h)) ++rank;   // stable, idx-asc ties
      }
      if (rank < need) {
        int p = atomicAdd(&occ[rr], 1);
        sel_idx[row * TOPK + nd + p] = h;
        sel_val[row * TOPK + nd + p] = v;
      }
    }
    const int nSel = nd + (need < na ? need : na);
    if (lane >= nSel && lane < TOPK) {         // pad (only when <32 positives)
      sel_idx[row * TOPK + lane] = 0;
      sel_val[row * TOPK + lane] = 0.f;
    }
  }
}

// ---------------- decode: out = b_dec + sum_32 val * WT[idx,:] (bf16 WT) ------
// v2: ushort4 (8B/lane) WT gather, float4 bias/accum/store, SGPR row base.
__global__ __launch_bounds__(192) void decode_kernel(
    const unsigned short* __restrict__ WT,   // [16384][768] bf16
    const int* __restrict__ sel_idx,
    const float* __restrict__ sel_val,
    const float* __restrict__ b_dec,
    float* __restrict__ out)                 // [8192][768]
{
  __shared__ int sidx[TOPK];
  __shared__ float sval[TOPK];
  const int row = blockIdx.x, tid = threadIdx.x;
  if (tid < TOPK) {
    sidx[tid] = sel_idx[row * TOPK + tid];
    sval[tid] = sel_val[row * TOPK + tid];
  }
  __syncthreads();
  float4 a = ((const float4*)b_dec)[tid];
  #pragma unroll 8
  for (int s = 0; s < TOPK; ++s) {
    const int h = __builtin_amdgcn_readfirstlane(sidx[s]);
    const ushort4 wv = ((const ushort4*)(WT + (size_t)h * D_INPUT))[tid];
    const float v = sval[s];
    a.x += v * bf2f(wv.x);
    a.y += v * bf2f(wv.y);
    a.z += v * bf2f(wv.z);
    a.w += v * bf2f(wv.w);
  }
  ((float4*)(out + (size_t)row * D_INPUT))[tid] = a;
}

// ---------------- diagnostic fallback: out = broadcast b_dec ----------------
__global__ void diag_fill(const float* __restrict__ b_dec, float* __restrict__ out) {
  const int row = blockIdx.x, tid = threadIdx.x;
  float* o = out + (size_t)row * D_INPUT;
  o[tid] = b_dec[tid]; o[tid + 256] = b_dec[tid + 256]; o[tid + 512] = b_dec[tid + 512];
}

extern "C" void kernel_launch(void* const* d_in, const int* in_sizes, int n_in,
                              void* d_out, int out_size, void* d_ws, size_t ws_size,
                              hipStream_t stream) {
  (void)in_sizes; (void)n_in; (void)out_size;
  const float* x     = (const float*)d_in[0];
  const float* W_enc = (const float*)d_in[1];
  const float* b_enc = (const float*)d_in[2];
  const float* W_dec = (const float*)d_in[3];
  const float* b_dec = (const float*)d_in[4];
  float* out = (float*)d_out;

  // ws layout: fixed buffers (~62 MB) first, Z chunk buffer in the remainder
  auto aln = [](size_t v) { return (v + 255) & ~(size_t)255; };
  char* ws = (char*)d_ws;
  size_t oWT = 0;
  size_t oWb = aln(oWT + (size_t)D_HID * D_INPUT * 2);   // WT bf16: 24 MB
  size_t oXb = aln(oWb + (size_t)D_HID * D_INPUT * 2);   // Wb bf16: 24 MB
  size_t oSI = aln(oXb + (size_t)BATCH * D_INPUT * 2);   // Xb bf16: 12 MB
  size_t oSV = aln(oSI + (size_t)BATCH * TOPK * 4);      // sel_idx: 1 MB
  size_t oZ  = aln(oSV + (size_t)BATCH * TOPK * 4);      // sel_val: 1 MB

  unsigned short* WTb = (unsigned short*)(ws + oWT);
  unsigned short* Wb  = (unsigned short*)(ws + oWb);
  unsigned short* Xb  = (unsigned short*)(ws + oXb);
  int*   sel_idx = (int*)(ws + oSI);
  float* sel_val = (float*)(ws + oSV);
  unsigned short* Zb = (unsigned short*)(ws + oZ);

  size_t zcap = ws_size > oZ ? ws_size - oZ : 0;
  long long chunkL = (long long)(zcap / ((size_t)D_HID * 2));
  int chunk = (int)(chunkL & ~127LL);                    // multiple of 128 rows
  if (chunk > BATCH) chunk = BATCH;
  if (chunk <= 0) {                                      // ws too small: signal
    diag_fill<<<dim3(BATCH), 256, 0, stream>>>(b_dec, out);
    return;
  }

  cvt_f32_bf16<<<dim3(BATCH * D_INPUT / 4 / 256), 256, 0, stream>>>(
      x, Xb, BATCH * D_INPUT);
  cvt_f32_bf16<<<dim3(D_HID * D_INPUT / 4 / 256), 256, 0, stream>>>(
      W_enc, Wb, D_HID * D_INPUT);
  transpose_wdec<<<dim3(D_HID / 32, D_INPUT / 32), dim3(32, 8), 0, stream>>>(
      W_dec, WTb);

  for (int r0 = 0; r0 < BATCH; r0 += chunk) {
    const int rows = (BATCH - r0) < chunk ? (BATCH - r0) : chunk;  // multiple of 128
    encode_kernel<<<dim3(D_HID / 128, rows / 128), 256, 0, stream>>>(
        Xb + (size_t)r0 * D_INPUT, Wb, b_enc, Zb);
    topk_kernel<<<dim3(rows / ROWS_PB), 256, 0, stream>>>(
        Zb, x, W_enc, b_enc, sel_idx, sel_val, r0);
  }

  decode_kernel<<<dim3(BATCH), 192, 0, stream>>>(WTb, sel_idx, sel_val, b_dec, out);
}

// Round 3
// 836.895 us; speedup vs baseline: 1.6999x; 1.6999x over previous
//
#include <hip/hip_runtime.h>

#define D_INPUT 768
#define D_HID   16384
#define BATCH   8192
#define TOPK    32
#define CAP     768
#define KT_COLLECT 0x3F98u   // bf16(1.1875): candidate-collect threshold
#define KT_STRONG  0x3FA0u   // bf16(1.25)  : fast-path validity guard (>= collect + MARGIN)

using f32x4     = __attribute__((ext_vector_type(4))) float;
using bf16x8    = __attribute__((ext_vector_type(8))) __bf16;
using ushort8_t = __attribute__((ext_vector_type(8))) unsigned short;

__device__ __forceinline__ unsigned short f2bf(float f) {
  union { float f; unsigned u; } v{f};
  return (unsigned short)((v.u + 0x7FFFu + ((v.u >> 16) & 1u)) >> 16);  // RNE
}
__device__ __forceinline__ float bf2f(unsigned short u) {
  union { unsigned u; float f; } v{(unsigned)u << 16};
  return v.f;
}

// async global->LDS, 16B per lane; LDS dest = wave-uniform base + lane*16.
__device__ __forceinline__ void async_copy16(const void* g, void* l) {
  __builtin_amdgcn_global_load_lds(
      (__attribute__((address_space(1))) void*)(unsigned long long)g,
      (__attribute__((address_space(3))) void*)(unsigned)(unsigned long long)l,
      16, 0, 0);
}

// Barrier that waits LDS ops only (lgkmcnt) and leaves global loads (vmcnt)
// in flight. All intra-block communication in topk is via LDS, so this is
// sufficient (m139/m201 pattern); register-load consumers get their own
// compiler-inserted vmcnt waits.
#define BAR() do {                                            \
    asm volatile("s_waitcnt lgkmcnt(0)" ::: "memory");        \
    __builtin_amdgcn_s_barrier();                             \
    asm volatile("" ::: "memory");                            \
  } while (0)

// Replica of OpenBLAS sgemm on Zen4/Zen5 hosts (SkylakeX/Cooperlake kernels):
// SGEMM_DEFAULT_Q = 320 -> K panels [320, 224, 224]; each panel a single
// ascending fma chain; C updated panel-by-panel -> ((p0 + p1) + p2).
// The three chains are INDEPENDENT -> interleaved for 3-way ILP (each chain's
// internal order untouched -> bit-identical result).
__device__ float blas_dot(const float* __restrict__ xr,
                          const float* __restrict__ wp) {
  float p0 = 0.f, p1 = 0.f, p2 = 0.f;
  #pragma unroll 4
  for (int i = 0; i < 224; ++i) {
    p0 = __builtin_fmaf(xr[i],       wp[i],       p0);
    p1 = __builtin_fmaf(xr[320 + i], wp[320 + i], p1);
    p2 = __builtin_fmaf(xr[544 + i], wp[544 + i], p2);
  }
  #pragma unroll 4
  for (int i = 224; i < 320; ++i) p0 = __builtin_fmaf(xr[i], wp[i], p0);
  return (p0 + p1) + p2;
}

// ---------------- fp32 -> bf16 convert (vectorized) ----------------
__global__ void cvt_f32_bf16(const float* __restrict__ in,
                             unsigned short* __restrict__ out, int n) {
  int i = (blockIdx.x * 256 + threadIdx.x) * 4;
  if (i < n) {
    float4 f = *(const float4*)(in + i);
    ushort4 o;
    o.x = f2bf(f.x); o.y = f2bf(f.y); o.z = f2bf(f.z); o.w = f2bf(f.w);
    *(ushort4*)(out + i) = o;
  }
}

// ---------------- W_dec [768][16384] -> WT bf16 [16384][768] ----------------
__global__ void transpose_wdec(const float* __restrict__ W,
                               unsigned short* __restrict__ WT) {
  __shared__ float tile[32][33];
  const int h0 = blockIdx.x * 32;   // hidden
  const int i0 = blockIdx.y * 32;   // d_in
  const int tx = threadIdx.x, ty = threadIdx.y;  // 32 x 8
  #pragma unroll
  for (int j = 0; j < 32; j += 8)
    tile[ty + j][tx] = W[(size_t)(i0 + ty + j) * D_HID + h0 + tx];
  __syncthreads();
  #pragma unroll
  for (int j = 0; j < 32; j += 8)
    WT[(size_t)(h0 + ty + j) * D_INPUT + i0 + tx] = f2bf(tile[tx][ty + j]);
}

// ---------------- encode: Z = relu(Xc * Wb^T + b_enc), bf16 MFMA ----------------
__global__ __launch_bounds__(256) void encode_kernel(
    const unsigned short* __restrict__ Xc,   // [rows][768] bf16 (chunk base)
    const unsigned short* __restrict__ Wb,   // [16384][768] bf16
    const float* __restrict__ b_enc,
    unsigned short* __restrict__ Z)          // [rows][16384] bf16, relu'd
{
  __shared__ unsigned short As[128 * 32];  // 8 KB, row-major [row][k]
  __shared__ unsigned short Bs[128 * 32];

  const int tid  = threadIdx.x;
  const int wave = tid >> 6;
  const int lane = tid & 63;
  const int tileN = blockIdx.x;
  const int tileM = blockIdx.y;

  const int e0 = wave * 512 + lane * 8;
  const int r0 = e0 >> 5;          // tile row 0..63 (second copy adds 64)
  const int k0 = e0 & 31;

  const unsigned short* gA = Xc + (size_t)(tileM * 128 + r0) * D_INPUT + k0;
  const unsigned short* gB = Wb + (size_t)(tileN * 128 + r0) * D_INPUT + k0;
  unsigned short* lA0 = As + wave * 512;         // wave-uniform LDS bases
  unsigned short* lA1 = As + wave * 512 + 2048;
  unsigned short* lB0 = Bs + wave * 512;
  unsigned short* lB1 = Bs + wave * 512 + 2048;

  const int wr = wave >> 1, wc = wave & 1;
  const int lrow = lane & 15;
  const int lk   = (lane >> 4) * 8;

  f32x4 acc[4][4] = {};

  for (int kt = 0; kt < D_INPUT / 32; ++kt) {
    __syncthreads();
    async_copy16(gA, lA0);
    async_copy16(gA + 64 * D_INPUT, lA1);
    async_copy16(gB, lB0);
    async_copy16(gB + 64 * D_INPUT, lB1);
    gA += 32; gB += 32;
    __builtin_amdgcn_s_waitcnt(0);
    __syncthreads();

    bf16x8 af[4], bfr[4];
    #pragma unroll
    for (int mf = 0; mf < 4; ++mf)
      af[mf] = __builtin_bit_cast(bf16x8,
        *(const ushort8_t*)(As + (wr * 64 + mf * 16 + lrow) * 32 + lk));
    #pragma unroll
    for (int nf = 0; nf < 4; ++nf)
      bfr[nf] = __builtin_bit_cast(bf16x8,
        *(const ushort8_t*)(Bs + (wc * 64 + nf * 16 + lrow) * 32 + lk));
    #pragma unroll
    for (int mf = 0; mf < 4; ++mf)
      #pragma unroll
      for (int nf = 0; nf < 4; ++nf)
        acc[mf][nf] = __builtin_amdgcn_mfma_f32_16x16x32_bf16(
            af[mf], bfr[nf], acc[mf][nf], 0, 0, 0);
  }

  // epilogue: C/D layout col=lane&15, row=(lane>>4)*4+reg (m89/m91-verified)
  const int rowBase = tileM * 128 + wr * 64;
  const int colBase = tileN * 128 + wc * 64;
  #pragma unroll
  for (int nf = 0; nf < 4; ++nf) {
    const int col = colBase + nf * 16 + lrow;
    const float bias = b_enc[col];
    #pragma unroll
    for (int mf = 0; mf < 4; ++mf) {
      const int row = rowBase + mf * 16 + (lane >> 4) * 4;
      #pragma unroll
      for (int i = 0; i < 4; ++i) {
        float v = acc[mf][nf][i] + bias;
        v = v > 0.f ? v : 0.f;
        Z[(size_t)(row + i) * D_HID + col] = f2bf(v);
      }
    }
  }
}

// Wave-0 suffix scan over a 256-bin histogram: find the highest bin b such
// that base + count(bins > b) + count(bin b) >= TOPK. Writes {bin, count
// strictly above bin} from the single winning lane.
__device__ __forceinline__ void scan_suffix(const unsigned int* __restrict__ h,
                                            int base, int* outBin, int* outCum,
                                            int l) {
  unsigned int h0 = h[255 - 4 * l];
  unsigned int h1 = h[254 - 4 * l];
  unsigned int h2 = h[253 - 4 * l];
  unsigned int h3 = h[252 - 4 * l];
  unsigned int c0 = h0, c1 = c0 + h1, c2 = c1 + h2, c3 = c2 + h3;
  unsigned int inc = c3;                       // inclusive scan of lane totals
  #pragma unroll
  for (int d = 1; d < 64; d <<= 1) {
    unsigned int o = __shfl_up(inc, d, 64);
    if (l >= d) inc += o;
  }
  unsigned int excl = (unsigned int)base + inc - c3;  // count above lane's bins
  int bFound = -1; int cumB = 0;
  if      (excl + c0 >= TOPK) { bFound = 255 - 4 * l; cumB = (int)excl; }
  else if (excl + c1 >= TOPK) { bFound = 254 - 4 * l; cumB = (int)(excl + c0); }
  else if (excl + c2 >= TOPK) { bFound = 253 - 4 * l; cumB = (int)(excl + c1); }
  else if (excl + c3 >= TOPK) { bFound = 252 - 4 * l; cumB = (int)(excl + c2); }
  unsigned long long m = __ballot(bFound >= 0);
  if (m) {
    int w = (int)__builtin_ctzll(m);           // lowest lane = highest bins
    if (l == w) { *outBin = bFound; *outCum = cumB; }
  } else if (l == 0) { *outBin = -1; *outCum = base; }
}

// ---------------- top-32 per row, candidate-compaction version ---------------
// v4: R1 did three full 16K sweeps (2 histogram passes + collection) with
// ~16K LDS atomics/row. Since only elements near/above the rank-32 value
// matter, ONE sweep compacts elements >= bf16(1.1875) into a <=768-entry LDS
// list (~300 expected for this data); the exact two-level bf16 histogram,
// threshold and MARGIN-band classification then run over the list only.
// Validity guard (block-uniform): count(k >= bf16(1.25)) >= 32 proves
// v32 >= 1.25, so every element of [v32-MARGIN, inf) lies above the collect
// threshold -> candidate set provably complete. Otherwise (or on list
// overflow) an exactness-preserving full-histogram fallback runs. Selection
// semantics identical to R1 in both paths.
__global__ __launch_bounds__(256) void topk_kernel(
    const unsigned short* __restrict__ Z,    // chunk base [rows][16384]
    const float* __restrict__ X,             // full fp32 [8192][768]
    const float* __restrict__ W_enc,         // fp32 [16384][768]
    const float* __restrict__ b_enc,
    int* __restrict__ sel_idx,               // [8192][32]
    float* __restrict__ sel_val,
    int rowOff)
{
  __shared__ float xrow[D_INPUT];            // 3 KB
  __shared__ unsigned int cand[CAP];         // 3 KB, (k<<16)|idx
  __shared__ unsigned int hist[512];         // [0..255] lvl-1, [256..511] lvl-2
  __shared__ int sB, sCum, sLo;
  __shared__ int cnt, cntS;
  __shared__ int def_cnt, amb_cnt, out_cnt;
  __shared__ int   def_idx[40];
  __shared__ float def_val[40];
  __shared__ int   amb_idx[64];
  __shared__ float amb_val[64];

  const int lrowB = blockIdx.x;            // row within chunk
  const int row   = rowOff + lrowB;        // absolute row
  const int tid   = threadIdx.x;

  // Z row -> registers (direct static indexing only -- no pointer passing)
  ushort8_t zv[8];
  {
    const ushort8_t* src = (const ushort8_t*)(Z + (size_t)lrowB * D_HID);
    #pragma unroll
    for (int j = 0; j < 8; ++j) zv[j] = src[tid + j * 256];
  }
  if (tid < D_INPUT / 4)
    ((float4*)xrow)[tid] = ((const float4*)(X + (size_t)row * D_INPUT))[tid];
  hist[tid] = 0; hist[tid + 256] = 0;
  if (tid == 0) { cnt = 0; cntS = 0; def_cnt = 0; amb_cnt = 0; out_cnt = 0; sLo = 0; }
  BAR();

  // ---- single sweep: compact candidates (positive bf16 order == bit order) ----
  int nS = 0;
  #pragma unroll
  for (int j = 0; j < 8; ++j)
    #pragma unroll
    for (int e = 0; e < 8; ++e) {
      const unsigned k = (unsigned short)zv[j][e];
      if (k >= KT_COLLECT) {
        const int p = atomicAdd(&cnt, 1);
        if (p < CAP) cand[p] = (k << 16) | (unsigned)(tid * 8 + j * 2048 + e);
        nS += (k >= KT_STRONG) ? 1 : 0;
      }
    }
  if (nS) atomicAdd(&cntS, nS);
  BAR();

  const bool fast = (cntS >= TOPK) && (cnt <= CAP);   // block-uniform
  const int  nC   = cnt < CAP ? cnt : CAP;

  if (fast) {
    // two-level exact bf16 threshold over the candidate list only
    for (int c = tid; c < nC; c += 256) atomicAdd(&hist[cand[c] >> 24], 1u);
    BAR();
    if (tid < 64) scan_suffix(hist, 0, &sB, &sCum, tid);
    BAR();
    {
      const int bHi = sB, cum1 = sCum;
      for (int c = tid; c < nC; c += 256) {
        const unsigned u = cand[c];
        if ((int)(u >> 24) == bHi) atomicAdd(&hist[256 + ((u >> 16) & 255u)], 1u);
      }
      BAR();
      if (tid < 64) { int d_; scan_suffix(hist + 256, cum1, &sLo, &d_, tid); }
      BAR();
    }
  } else {
    // ---- fallback: full two-level histogram over all 16K (R1 semantics) ----
    #pragma unroll
    for (int j = 0; j < 8; ++j)
      #pragma unroll
      for (int e = 0; e < 8; ++e) {
        const unsigned k = (unsigned short)zv[j][e];
        if (k) atomicAdd(&hist[k >> 8], 1u);
      }
    BAR();
    if (tid < 64) scan_suffix(hist, 0, &sB, &sCum, tid);
    BAR();
    {
      const int bHi = sB, cum1 = sCum;
      if (bHi >= 0) {
        #pragma unroll
        for (int j = 0; j < 8; ++j)
          #pragma unroll
          for (int e = 0; e < 8; ++e) {
            const unsigned k = (unsigned short)zv[j][e];
            if (k && (int)(k >> 8) == bHi) atomicAdd(&hist[256 + (k & 255u)], 1u);
          }
      }
      BAR();
      if (sB >= 0) {
        if (tid < 64) { int d_; scan_suffix(hist + 256, cum1, &sLo, &d_, tid); }
      }
      BAR();
    }
  }

  const int T = (sB >= 0) ? ((sB << 8) | sLo) : 0;
  const bool deg = (T == 0);              // fewer than 32 positive activations
  const float v32 = bf2f((unsigned short)T);
  const float MARGIN = 0.025f;            // > 2*(bf16 quant 0.0078 + MFMA noise)
  const float vhi = v32 + MARGIN, vlo = v32 - MARGIN;

  // ---- classification ----
  if (fast) {                              // fast => not deg
    for (int c = tid; c < nC; c += 256) {
      const unsigned u = cand[c];
      const float v = bf2f((unsigned short)(u >> 16));
      const int i = (int)(u & 0xFFFFu);
      if (v > vhi) {                       // provably in ref's top-32
        const int p = atomicAdd(&def_cnt, 1);
        if (p < 40) def_idx[p] = i;
      } else if (v >= vlo) {               // boundary-ambiguous
        const int p = atomicAdd(&amb_cnt, 1);
        if (p < 64) amb_idx[p] = i;
      }
    }
  } else {
    #pragma unroll
    for (int j = 0; j < 8; ++j)
      #pragma unroll
      for (int e = 0; e < 8; ++e) {
        const unsigned k = (unsigned short)zv[j][e];
        if (!k) continue;
        const float v = bf2f((unsigned short)k);
        const int i = tid * 8 + j * 2048 + e;
        if (deg || v > vhi) {
          const int p = atomicAdd(&def_cnt, 1);
          if (p < 40) def_idx[p] = i;
        } else if (v >= vlo) {
          const int p = atomicAdd(&amb_cnt, 1);
          if (p < 64) amb_idx[p] = i;
        }
      }
  }
  BAR();

  const int nAmb = deg ? 0 : (amb_cnt < 64 ? amb_cnt : 64);
  const int nDef = def_cnt < 40 ? def_cnt : 40;

  // OpenBLAS-replica fp32 recompute: one THREAD per candidate (def + amb).
  for (int c = tid; c < nDef + nAmb; c += 256) {
    const int h = (c < nDef) ? def_idx[c] : amb_idx[c - nDef];
    float acc = blas_dot(xrow, W_enc + (size_t)h * D_INPUT) + b_enc[h];
    float v = acc > 0.f ? acc : 0.f;
    if (c < nDef) def_val[c] = v; else amb_val[c - nDef] = v;
  }
  BAR();

  const int need = TOPK - nDef;
  if (tid < nDef) {
    sel_idx[row * TOPK + tid] = def_idx[tid];
    sel_val[row * TOPK + tid] = def_val[tid];
  }
  if (tid < nAmb) {
    const float v = amb_val[tid];
    const int h = amb_idx[tid];
    int rank = 0;
    for (int j = 0; j < nAmb; ++j) {
      const float vj = amb_val[j];
      if (vj > v || (vj == v && amb_idx[j] < h)) ++rank;   // stable, idx-asc ties
    }
    if (rank < need) {
      int p = atomicAdd(&out_cnt, 1);
      sel_idx[row * TOPK + nDef + p] = h;
      sel_val[row * TOPK + nDef + p] = v;
    }
  }
  BAR();
  const int nSel = nDef + (need < nAmb ? need : nAmb);
  if (tid >= nSel && tid < TOPK) {         // pad (only when <32 positives)
    sel_idx[row * TOPK + tid] = 0;
    sel_val[row * TOPK + tid] = 0.f;
  }
}

// ---------------- decode: out = b_dec + sum_32 val * WT[idx,:] (bf16 WT) ------
__global__ __launch_bounds__(256) void decode_kernel(
    const unsigned short* __restrict__ WT,   // [16384][768] bf16
    const int* __restrict__ sel_idx,
    const float* __restrict__ sel_val,
    const float* __restrict__ b_dec,
    float* __restrict__ out)                 // [8192][768]
{
  __shared__ int sidx[TOPK];
  __shared__ float sval[TOPK];
  const int row = blockIdx.x, tid = threadIdx.x;
  if (tid < TOPK) {
    sidx[tid] = sel_idx[row * TOPK + tid];
    sval[tid] = sel_val[row * TOPK + tid];
  }
  __syncthreads();
  float a0 = b_dec[tid], a1 = b_dec[tid + 256], a2 = b_dec[tid + 512];
  #pragma unroll 8
  for (int s = 0; s < TOPK; ++s) {
    const unsigned short* w = WT + (size_t)sidx[s] * D_INPUT;
    const float v = sval[s];
    a0 += v * bf2f(w[tid]);
    a1 += v * bf2f(w[tid + 256]);
    a2 += v * bf2f(w[tid + 512]);
  }
  float* o = out + (size_t)row * D_INPUT;
  o[tid] = a0; o[tid + 256] = a1; o[tid + 512] = a2;
}

// ---------------- diagnostic fallback: out = broadcast b_dec ----------------
__global__ void diag_fill(const float* __restrict__ b_dec, float* __restrict__ out) {
  const int row = blockIdx.x, tid = threadIdx.x;
  float* o = out + (size_t)row * D_INPUT;
  o[tid] = b_dec[tid]; o[tid + 256] = b_dec[tid + 256]; o[tid + 512] = b_dec[tid + 512];
}

extern "C" void kernel_launch(void* const* d_in, const int* in_sizes, int n_in,
                              void* d_out, int out_size, void* d_ws, size_t ws_size,
                              hipStream_t stream) {
  (void)in_sizes; (void)n_in; (void)out_size;
  const float* x     = (const float*)d_in[0];
  const float* W_enc = (const float*)d_in[1];
  const float* b_enc = (const float*)d_in[2];
  const float* W_dec = (const float*)d_in[3];
  const float* b_dec = (const float*)d_in[4];
  float* out = (float*)d_out;

  // ws layout: fixed buffers (~62 MB) first, Z chunk buffer in the remainder
  auto aln = [](size_t v) { return (v + 255) & ~(size_t)255; };
  char* ws = (char*)d_ws;
  size_t oWT = 0;
  size_t oWb = aln(oWT + (size_t)D_HID * D_INPUT * 2);   // WT bf16: 24 MB
  size_t oXb = aln(oWb + (size_t)D_HID * D_INPUT * 2);   // Wb bf16: 24 MB
  size_t oSI = aln(oXb + (size_t)BATCH * D_INPUT * 2);   // Xb bf16: 12 MB
  size_t oSV = aln(oSI + (size_t)BATCH * TOPK * 4);      // sel_idx: 1 MB
  size_t oZ  = aln(oSV + (size_t)BATCH * TOPK * 4);      // sel_val: 1 MB

  unsigned short* WTb = (unsigned short*)(ws + oWT);
  unsigned short* Wb  = (unsigned short*)(ws + oWb);
  unsigned short* Xb  = (unsigned short*)(ws + oXb);
  int*   sel_idx = (int*)(ws + oSI);
  float* sel_val = (float*)(ws + oSV);
  unsigned short* Zb = (unsigned short*)(ws + oZ);

  size_t zcap = ws_size > oZ ? ws_size - oZ : 0;
  long long chunkL = (long long)(zcap / ((size_t)D_HID * 2));
  int chunk = (int)(chunkL & ~127LL);                    // multiple of 128 rows
  if (chunk > BATCH) chunk = BATCH;
  if (chunk <= 0) {                                      // ws too small: signal
    diag_fill<<<dim3(BATCH), 256, 0, stream>>>(b_dec, out);
    return;
  }

  cvt_f32_bf16<<<dim3(BATCH * D_INPUT / 4 / 256), 256, 0, stream>>>(
      x, Xb, BATCH * D_INPUT);
  cvt_f32_bf16<<<dim3(D_HID * D_INPUT / 4 / 256), 256, 0, stream>>>(
      W_enc, Wb, D_HID * D_INPUT);
  transpose_wdec<<<dim3(D_HID / 32, D_INPUT / 32), dim3(32, 8), 0, stream>>>(
      W_dec, WTb);

  for (int r0 = 0; r0 < BATCH; r0 += chunk) {
    const int rows = (BATCH - r0) < chunk ? (BATCH - r0) : chunk;  // multiple of 128
    encode_kernel<<<dim3(D_HID / 128, rows / 128), 256, 0, stream>>>(
        Xb + (size_t)r0 * D_INPUT, Wb, b_enc, Zb);
    topk_kernel<<<dim3(rows), 256, 0, stream>>>(
        Zb, x, W_enc, b_enc, sel_idx, sel_val, r0);
  }

  decode_kernel<<<dim3(BATCH), 256, 0, stream>>>(WTb, sel_idx, sel_val, b_dec, out);
}